// Round 4
// baseline (203.683 us; speedup 1.0000x reference)
//
#include <hip/hip_runtime.h>
#include <stdint.h>

#define NQ 8192
#define NK 8192
#define DIN 32

#define BT 256                 // threads per block (4 waves)
#define RPW 4                  // q-rows per wave (4 interleaved hash chains)
#define ROWS_PER_BLOCK 16      // 4 waves * RPW

// keep  <=>  (bits >> 9) < 6710887  <=>  bits < 6710887*512  (bit-exact, verified r2/r3)
#define KEEP_BITS 3435974144u
// fold 1/16 (score scale) and log2(e) into q so e = exp2(dot(qs, k))
#define QSCALE 0.09016844005556021f

// ---------------- threefry2x32-20, JAX partitionable path ----------------
// key = jax.random.key(42) -> (0, 42); counter (hi,lo) = (0, flat_idx)
// bits = out0 ^ out1. Algebraically identical to the verified r2/r3 schedule:
//  - round 1 simplified via x0_init = 0
//  - key injections folded into the following round's x0 add (v_add3)
__device__ __forceinline__ uint32_t rotl(uint32_t v, int d) {
    return __builtin_amdgcn_alignbit(v, v, 32 - d);   // 1 VALU op
}

__device__ __forceinline__ void tf_round(uint32_t x0[4], uint32_t x1[4], int d) {
#pragma unroll
    for (int j = 0; j < 4; ++j) {
        x0[j] += x1[j];
        x1[j] = rotl(x1[j], d) ^ x0[j];
    }
}

// equivalent to {x0 += c0; x1 += c1;} followed by tf_round(d)
__device__ __forceinline__ void tf_round_inj(uint32_t x0[4], uint32_t x1[4],
                                             uint32_t c0, uint32_t c1, int d) {
#pragma unroll
    for (int j = 0; j < 4; ++j) {
        x1[j] += c1;
        x0[j] = x0[j] + c0 + x1[j];       // 3-way add -> v_add3_u32
        x1[j] = rotl(x1[j], d) ^ x0[j];
    }
}

// 4 independent hashes for counters ctr + j*NK (j = row index within wave)
__device__ __forceinline__ void threefry4(uint32_t ctr, uint32_t bits[4]) {
    const uint32_t ks1 = 42u;
    const uint32_t ks2 = 0x1BD11BDAu ^ 42u;
    uint32_t x0[4], x1[4];
#pragma unroll
    for (int j = 0; j < 4; ++j) {
        const uint32_t t = ctr + ((uint32_t)j * (uint32_t)NK + ks1);
        x0[j] = t;                         // round 1: x0 = 0 + x1
        x1[j] = rotl(t, 13) ^ t;
    }
    tf_round(x0, x1, 15); tf_round(x0, x1, 26); tf_round(x0, x1, 6);
    tf_round_inj(x0, x1, ks1, ks2 + 1u, 17);
    tf_round(x0, x1, 29); tf_round(x0, x1, 16); tf_round(x0, x1, 24);
    tf_round_inj(x0, x1, ks2, 2u, 13);
    tf_round(x0, x1, 15); tf_round(x0, x1, 26); tf_round(x0, x1, 6);
    tf_round_inj(x0, x1, 0u, ks1 + 3u, 17);
    tf_round(x0, x1, 29); tf_round(x0, x1, 16); tf_round(x0, x1, 24);
    tf_round_inj(x0, x1, ks1, ks2 + 4u, 13);
    tf_round(x0, x1, 15); tf_round(x0, x1, 26); tf_round(x0, x1, 6);
#pragma unroll
    for (int j = 0; j < 4; ++j)
        bits[j] = (x0[j] + ks2) ^ (x1[j] + 5u);
}

__device__ __forceinline__ float fexp2(float x) {
#if __has_builtin(__builtin_amdgcn_exp2f)
    return __builtin_amdgcn_exp2f(x);
#else
    return __expf(0.6931471805599453f * x);
#endif
}

// ---------------- tiny projection: out[r][c] = x[r][:] . w[c][:] + b[c] --
__global__ void proj_kernel(const float* __restrict__ x,
                            const float* __restrict__ w,
                            const float* __restrict__ b,
                            float* __restrict__ out, int dout) {
    __shared__ __align__(16) float ws[8 * DIN];
    __shared__ float bs[8];
    const int tid = threadIdx.x;
    if (tid < dout * DIN) ws[tid] = w[tid];
    if (tid < dout) bs[tid] = b[tid];
    __syncthreads();

    const int row = blockIdx.x * BT + tid;
    const float4* xr = reinterpret_cast<const float4*>(x + (size_t)row * DIN);
    float4 xv[8];
#pragma unroll
    for (int i = 0; i < 8; ++i) xv[i] = xr[i];

    for (int c = 0; c < dout; ++c) {
        float s = bs[c];
#pragma unroll
        for (int i = 0; i < 8; ++i) {
            const float4 wv = *reinterpret_cast<const float4*>(&ws[c * DIN + i * 4]);
            s += xv[i].x * wv.x + xv[i].y * wv.y + xv[i].z * wv.z + xv[i].w * wv.w;
        }
        out[(size_t)row * dout + c] = s;
    }
}

// ---------------- fused scores+softmax+dropout+PV (k-split partials) -----
// No LDS: k/v (384 KB) are L2-resident; loads are fully coalesced.
__global__ __launch_bounds__(BT, 4) void attn_kernel(
    const float* __restrict__ q,        // [NQ][4] (projection output)
    const float* __restrict__ k,        // [NK][4]
    const float* __restrict__ v,        // [NK][8]
    float* __restrict__ partial,        // [ksplit][NQ][12]: 8 nums, den
    int ksplit) {
    const int tid = threadIdx.x;
    const int lane = tid & 63;
    const int wave = tid >> 6;
    const int split = blockIdx.y;
    const int qbase = blockIdx.x * ROWS_PER_BLOCK + wave * RPW;
    const int klen = NK / ksplit;
    const int kstart = split * klen;

    float4 qs[RPW];
#pragma unroll
    for (int r = 0; r < RPW; ++r) {
        const float4 t = *reinterpret_cast<const float4*>(q + (size_t)(qbase + r) * 4);
        qs[r] = make_float4(t.x * QSCALE, t.y * QSCALE, t.z * QSCALE, t.w * QSCALE);
    }

    float4 accA[RPW], accB[RPW];
    float den[RPW];
#pragma unroll
    for (int r = 0; r < RPW; ++r) {
        accA[r] = make_float4(0.f, 0.f, 0.f, 0.f);
        accB[r] = make_float4(0.f, 0.f, 0.f, 0.f);
        den[r] = 0.f;
    }

    const float4* kp = reinterpret_cast<const float4*>(k) + (kstart + lane);
    const float4* vp = reinterpret_cast<const float4*>(v) + 2 * (size_t)(kstart + lane);
    uint32_t ctr = (uint32_t)qbase * (uint32_t)NK + (uint32_t)(kstart + lane);

    const int iters = klen / 64;
    for (int it = 0; it < iters; ++it) {
        const float4 kv = kp[(size_t)it * 64];
        const float4 va = vp[(size_t)it * 128];
        const float4 vb = vp[(size_t)it * 128 + 1];

        uint32_t bits[RPW];
        threefry4(ctr, bits);
        ctr += 64;

        float e[RPW];
#pragma unroll
        for (int r = 0; r < RPW; ++r) {
            const float s = qs[r].x * kv.x + qs[r].y * kv.y +
                            qs[r].z * kv.z + qs[r].w * kv.w;
            e[r] = fexp2(s);
        }
#pragma unroll
        for (int r = 0; r < RPW; ++r) {
            const float w = (bits[r] < KEEP_BITS) ? e[r] : 0.0f;
            den[r] += e[r];
            accA[r].x += w * va.x; accA[r].y += w * va.y;
            accA[r].z += w * va.z; accA[r].w += w * va.w;
            accB[r].x += w * vb.x; accB[r].y += w * vb.y;
            accB[r].z += w * vb.z; accB[r].w += w * vb.w;
        }
    }

    // wave-level reduction of 9 accumulators per row, write partials
#pragma unroll
    for (int r = 0; r < RPW; ++r) {
        float n0 = accA[r].x, n1 = accA[r].y, n2 = accA[r].z, n3 = accA[r].w;
        float n4 = accB[r].x, n5 = accB[r].y, n6 = accB[r].z, n7 = accB[r].w;
        float dd = den[r];
#pragma unroll
        for (int off = 32; off >= 1; off >>= 1) {
            n0 += __shfl_xor(n0, off); n1 += __shfl_xor(n1, off);
            n2 += __shfl_xor(n2, off); n3 += __shfl_xor(n3, off);
            n4 += __shfl_xor(n4, off); n5 += __shfl_xor(n5, off);
            n6 += __shfl_xor(n6, off); n7 += __shfl_xor(n7, off);
            dd += __shfl_xor(dd, off);
        }
        if (lane == 0) {
            float* p = partial + ((size_t)split * NQ + (size_t)(qbase + r)) * 12;
            p[0] = n0; p[1] = n1; p[2] = n2; p[3] = n3;
            p[4] = n4; p[5] = n5; p[6] = n6; p[7] = n7;
            p[8] = dd;
        }
    }
}

// ---------------- combine partials + final normalize ---------------------
__global__ void combine_kernel(const float* __restrict__ partial,
                               float* __restrict__ out, int ksplit) {
    const int row = blockIdx.x * 256 + threadIdx.x;
    float n[8] = {0.f, 0.f, 0.f, 0.f, 0.f, 0.f, 0.f, 0.f};
    float dd = 0.f;
    for (int s = 0; s < ksplit; ++s) {
        const float* p = partial + ((size_t)s * NQ + (size_t)row) * 12;
#pragma unroll
        for (int j = 0; j < 8; ++j) n[j] += p[j];
        dd += p[8];
    }
    const float inv = 1.0f / (0.8f * dd);
#pragma unroll
    for (int j = 0; j < 8; ++j) out[(size_t)row * 8 + j] = n[j] * inv;
}

extern "C" void kernel_launch(void* const* d_in, const int* in_sizes, int n_in,
                              void* d_out, int out_size, void* d_ws, size_t ws_size,
                              hipStream_t stream) {
    const float* x1   = (const float*)d_in[0];
    const float* x2   = (const float*)d_in[1];
    const float* wq_w = (const float*)d_in[2];
    const float* wq_b = (const float*)d_in[3];
    const float* wk_w = (const float*)d_in[4];
    const float* wk_b = (const float*)d_in[5];
    const float* wv_w = (const float*)d_in[6];
    const float* wv_b = (const float*)d_in[7];
    float* out = (float*)d_out;

    // workspace: q [8192*4] | k [8192*4] | v [8192*8] | partial [ksplit][8192][12]
    float* qws = (float*)d_ws;
    float* kws = qws + (size_t)NQ * 4;
    float* vws = kws + (size_t)NK * 4;
    float* pws = vws + (size_t)NK * 8;

    const size_t qkv_bytes = ((size_t)NQ * 4 + NK * 4 + NK * 8) * sizeof(float);
    const size_t per_split = (size_t)NQ * 12 * sizeof(float);
    int ksplit = 4;
    while (ksplit > 1 && ws_size < qkv_bytes + (size_t)ksplit * per_split) ksplit >>= 1;

    proj_kernel<<<NQ / BT, BT, 0, stream>>>(x1, wq_w, wq_b, qws, 4);
    proj_kernel<<<NK / BT, BT, 0, stream>>>(x2, wk_w, wk_b, kws, 4);
    proj_kernel<<<NK / BT, BT, 0, stream>>>(x2, wv_w, wv_b, vws, 8);

    dim3 grid(NQ / ROWS_PER_BLOCK, ksplit);
    attn_kernel<<<grid, BT, 0, stream>>>(qws, kws, vws, pws, ksplit);

    combine_kernel<<<NQ / 256, 256, 0, stream>>>(pws, out, ksplit);
}

// Round 5
// 172.731 us; speedup vs baseline: 1.1792x; 1.1792x over previous
//
#include <hip/hip_runtime.h>
#include <stdint.h>

#define NQ 8192
#define NK 8192
#define DIN 32

#define BT 256                 // threads per block (4 waves)
#define RPW 4                  // q-rows per wave (4 interleaved hash chains)
#define ROWS_PER_BLOCK 16      // 4 waves * RPW

// keep  <=>  (bits >> 9) < 6710887  <=>  bits < 6710887*512  (bit-exact, verified r2-r4)
#define KEEP_BITS 3435974144u
// fold 1/16 (score scale) and log2(e) into q so e = exp2(dot(qs, k))
#define QSCALE 0.09016844005556021f

// ---------------- threefry2x32-20, JAX partitionable path ----------------
// key = jax.random.key(42) -> (0, 42); counter (hi,lo) = (0, flat_idx)
// bits = out0 ^ out1. Exact transcription of the r2-verified schedule into
// inline asm: rounds 2-20 + key injections = 256 pinned instructions for
// 4 chains. Round 1 (x0_init=0) and the final key add stay in C.
//
// rotl(x, r) == v_alignbit_b32(x, x, 32-r):
//   rot 13,15,26,6,17,29,16,24 -> shift 19,17,6,26,15,3,16,8
// ks1 = 42, ks2 = 0x1BD11BDA ^ 42 = 0x1BD11BF0

__device__ __forceinline__ uint32_t rotl(uint32_t v, int d) {
    return __builtin_amdgcn_alignbit(v, v, 32 - d);
}

// one threefry round for 4 chains; S = 32 - rotation
#define TF_ROUND(S) \
  "v_add_u32 %0,%0,%4\n v_alignbit_b32 %4,%4,%4," #S "\n v_xor_b32 %4,%4,%0\n" \
  "v_add_u32 %1,%1,%5\n v_alignbit_b32 %5,%5,%5," #S "\n v_xor_b32 %5,%5,%1\n" \
  "v_add_u32 %2,%2,%6\n v_alignbit_b32 %6,%6,%6," #S "\n v_xor_b32 %6,%6,%2\n" \
  "v_add_u32 %3,%3,%7\n v_alignbit_b32 %7,%7,%7," #S "\n v_xor_b32 %7,%7,%3\n"

// key injection into both halves (literals in src0 are legal for VOP2)
#define TF_INJ(C0, C1) \
  "v_add_u32 %0," #C0 ",%0\n v_add_u32 %4," #C1 ",%4\n" \
  "v_add_u32 %1," #C0 ",%1\n v_add_u32 %5," #C1 ",%5\n" \
  "v_add_u32 %2," #C0 ",%2\n v_add_u32 %6," #C1 ",%6\n" \
  "v_add_u32 %3," #C0 ",%3\n v_add_u32 %7," #C1 ",%7\n"

// injection with c0 == 0 (skip the no-op x0 adds)
#define TF_INJ1(C1) \
  "v_add_u32 %4," #C1 ",%4\n v_add_u32 %5," #C1 ",%5\n" \
  "v_add_u32 %6," #C1 ",%6\n v_add_u32 %7," #C1 ",%7\n"

__device__ __forceinline__ void threefry4(uint32_t ctr, uint32_t bits[4]) {
    uint32_t a0, a1, a2, a3, b0, b1, b2, b3;
    // round 1 (rot 13) with x0_init = 0:  x0 = t, x1 = rotl(t,13) ^ t
    {
        const uint32_t t0 = ctr + 42u;                 // j=0: 0*NK + ks1
        const uint32_t t1 = ctr + 8234u;               // j=1: NK + 42
        const uint32_t t2 = ctr + 16426u;              // j=2
        const uint32_t t3 = ctr + 24618u;              // j=3
        a0 = t0; b0 = rotl(t0, 13) ^ t0;
        a1 = t1; b1 = rotl(t1, 13) ^ t1;
        a2 = t2; b2 = rotl(t2, 13) ^ t2;
        a3 = t3; b3 = rotl(t3, 13) ^ t3;
    }
    asm volatile(
        TF_ROUND(17) TF_ROUND(6) TF_ROUND(26)          // rounds 2-4 (rot 15,26,6)
        TF_INJ(42, 0x1BD11BF1)                         // ks1, ks2+1
        TF_ROUND(15) TF_ROUND(3) TF_ROUND(16) TF_ROUND(8)   // rounds 5-8 (17,29,16,24)
        TF_INJ(0x1BD11BF0, 2)                          // ks2, 2
        TF_ROUND(19) TF_ROUND(17) TF_ROUND(6) TF_ROUND(26)  // rounds 9-12 (13,15,26,6)
        TF_INJ1(45)                                    // 0, ks1+3
        TF_ROUND(15) TF_ROUND(3) TF_ROUND(16) TF_ROUND(8)   // rounds 13-16 (17,29,16,24)
        TF_INJ(42, 0x1BD11BF4)                         // ks1, ks2+4
        TF_ROUND(19) TF_ROUND(17) TF_ROUND(6) TF_ROUND(26)  // rounds 17-20 (13,15,26,6)
        : "+v"(a0), "+v"(a1), "+v"(a2), "+v"(a3),
          "+v"(b0), "+v"(b1), "+v"(b2), "+v"(b3));
    bits[0] = (a0 + 0x1BD11BF0u) ^ (b0 + 5u);
    bits[1] = (a1 + 0x1BD11BF0u) ^ (b1 + 5u);
    bits[2] = (a2 + 0x1BD11BF0u) ^ (b2 + 5u);
    bits[3] = (a3 + 0x1BD11BF0u) ^ (b3 + 5u);
}

__device__ __forceinline__ float fexp2(float x) {
#if __has_builtin(__builtin_amdgcn_exp2f)
    return __builtin_amdgcn_exp2f(x);
#else
    return __expf(0.6931471805599453f * x);
#endif
}

// ---------------- tiny projection: out[r][c] = x[r][:] . w[c][:] + b[c] --
__global__ void proj_kernel(const float* __restrict__ x,
                            const float* __restrict__ w,
                            const float* __restrict__ b,
                            float* __restrict__ out, int dout) {
    __shared__ __align__(16) float ws[8 * DIN];
    __shared__ float bs[8];
    const int tid = threadIdx.x;
    if (tid < dout * DIN) ws[tid] = w[tid];
    if (tid < dout) bs[tid] = b[tid];
    __syncthreads();

    const int row = blockIdx.x * BT + tid;
    const float4* xr = reinterpret_cast<const float4*>(x + (size_t)row * DIN);
    float4 xv[8];
#pragma unroll
    for (int i = 0; i < 8; ++i) xv[i] = xr[i];

    for (int c = 0; c < dout; ++c) {
        float s = bs[c];
#pragma unroll
        for (int i = 0; i < 8; ++i) {
            const float4 wv = *reinterpret_cast<const float4*>(&ws[c * DIN + i * 4]);
            s += xv[i].x * wv.x + xv[i].y * wv.y + xv[i].z * wv.z + xv[i].w * wv.w;
        }
        out[(size_t)row * dout + c] = s;
    }
}

// ---------------- fused scores+softmax+dropout+PV (k-split partials) -----
// No LDS: k/v (384 KB) are L2-resident; loads fully coalesced; next
// iteration's k/v prefetched into registers before the 256-instr hash block.
__global__ __launch_bounds__(BT, 4) void attn_kernel(
    const float* __restrict__ q,        // [NQ][4] (projection output)
    const float* __restrict__ k,        // [NK][4]
    const float* __restrict__ v,        // [NK][8]
    float* __restrict__ partial,        // [ksplit][NQ][12]: 8 nums, den
    int ksplit) {
    const int tid = threadIdx.x;
    const int lane = tid & 63;
    const int wave = tid >> 6;
    const int split = blockIdx.y;
    const int qbase = blockIdx.x * ROWS_PER_BLOCK + wave * RPW;
    const int klen = NK / ksplit;
    const int kstart = split * klen;

    float4 qs[RPW];
#pragma unroll
    for (int r = 0; r < RPW; ++r) {
        const float4 t = *reinterpret_cast<const float4*>(q + (size_t)(qbase + r) * 4);
        qs[r] = make_float4(t.x * QSCALE, t.y * QSCALE, t.z * QSCALE, t.w * QSCALE);
    }

    float4 accA[RPW], accB[RPW];
    float den[RPW];
#pragma unroll
    for (int r = 0; r < RPW; ++r) {
        accA[r] = make_float4(0.f, 0.f, 0.f, 0.f);
        accB[r] = make_float4(0.f, 0.f, 0.f, 0.f);
        den[r] = 0.f;
    }

    const float4* kp = reinterpret_cast<const float4*>(k) + (kstart + lane);
    const float4* vp = reinterpret_cast<const float4*>(v) + 2 * (size_t)(kstart + lane);
    uint32_t ctr = (uint32_t)qbase * (uint32_t)NK + (uint32_t)(kstart + lane);

    const int iters = klen / 64;
    float4 kv = kp[0];
    float4 va = vp[0];
    float4 vb = vp[1];

    for (int it = 0; it < iters; ++it) {
        // prefetch next tile (reads ≤2KB past v on the last split's last
        // iter — lands in the partial region of d_ws, in-bounds, unused)
        const int nx = (it + 1 < iters) ? (it + 1) : it;
        const float4 kn  = kp[(size_t)nx * 64];
        const float4 van = vp[(size_t)nx * 128];
        const float4 vbn = vp[(size_t)nx * 128 + 1];

        uint32_t bits[RPW];
        threefry4(ctr, bits);
        ctr += 64;

        float e[RPW];
#pragma unroll
        for (int r = 0; r < RPW; ++r) {
            const float s = qs[r].x * kv.x + qs[r].y * kv.y +
                            qs[r].z * kv.z + qs[r].w * kv.w;
            e[r] = fexp2(s);
        }
#pragma unroll
        for (int r = 0; r < RPW; ++r) {
            const float w = (bits[r] < KEEP_BITS) ? e[r] : 0.0f;
            den[r] += e[r];
            accA[r].x += w * va.x; accA[r].y += w * va.y;
            accA[r].z += w * va.z; accA[r].w += w * va.w;
            accB[r].x += w * vb.x; accB[r].y += w * vb.y;
            accB[r].z += w * vb.z; accB[r].w += w * vb.w;
        }
        kv = kn; va = van; vb = vbn;
    }

    // wave-level reduction of 9 accumulators per row, write partials
#pragma unroll
    for (int r = 0; r < RPW; ++r) {
        float n0 = accA[r].x, n1 = accA[r].y, n2 = accA[r].z, n3 = accA[r].w;
        float n4 = accB[r].x, n5 = accB[r].y, n6 = accB[r].z, n7 = accB[r].w;
        float dd = den[r];
#pragma unroll
        for (int off = 32; off >= 1; off >>= 1) {
            n0 += __shfl_xor(n0, off); n1 += __shfl_xor(n1, off);
            n2 += __shfl_xor(n2, off); n3 += __shfl_xor(n3, off);
            n4 += __shfl_xor(n4, off); n5 += __shfl_xor(n5, off);
            n6 += __shfl_xor(n6, off); n7 += __shfl_xor(n7, off);
            dd += __shfl_xor(dd, off);
        }
        if (lane == 0) {
            float* p = partial + ((size_t)split * NQ + (size_t)(qbase + r)) * 12;
            p[0] = n0; p[1] = n1; p[2] = n2; p[3] = n3;
            p[4] = n4; p[5] = n5; p[6] = n6; p[7] = n7;
            p[8] = dd;
        }
    }
}

// ---------------- combine partials + final normalize ---------------------
__global__ void combine_kernel(const float* __restrict__ partial,
                               float* __restrict__ out, int ksplit) {
    const int row = blockIdx.x * 256 + threadIdx.x;
    float n[8] = {0.f, 0.f, 0.f, 0.f, 0.f, 0.f, 0.f, 0.f};
    float dd = 0.f;
    for (int s = 0; s < ksplit; ++s) {
        const float* p = partial + ((size_t)s * NQ + (size_t)row) * 12;
#pragma unroll
        for (int j = 0; j < 8; ++j) n[j] += p[j];
        dd += p[8];
    }
    const float inv = 1.0f / (0.8f * dd);
#pragma unroll
    for (int j = 0; j < 8; ++j) out[(size_t)row * 8 + j] = n[j] * inv;
}

extern "C" void kernel_launch(void* const* d_in, const int* in_sizes, int n_in,
                              void* d_out, int out_size, void* d_ws, size_t ws_size,
                              hipStream_t stream) {
    const float* x1   = (const float*)d_in[0];
    const float* x2   = (const float*)d_in[1];
    const float* wq_w = (const float*)d_in[2];
    const float* wq_b = (const float*)d_in[3];
    const float* wk_w = (const float*)d_in[4];
    const float* wk_b = (const float*)d_in[5];
    const float* wv_w = (const float*)d_in[6];
    const float* wv_b = (const float*)d_in[7];
    float* out = (float*)d_out;

    // workspace: q [8192*4] | k [8192*4] | v [8192*8] | partial [ksplit][8192][12]
    float* qws = (float*)d_ws;
    float* kws = qws + (size_t)NQ * 4;
    float* vws = kws + (size_t)NK * 4;
    float* pws = vws + (size_t)NK * 8;

    const size_t qkv_bytes = ((size_t)NQ * 4 + NK * 4 + NK * 8) * sizeof(float);
    const size_t per_split = (size_t)NQ * 12 * sizeof(float);
    int ksplit = 4;
    while (ksplit > 1 && ws_size < qkv_bytes + (size_t)ksplit * per_split) ksplit >>= 1;

    proj_kernel<<<NQ / BT, BT, 0, stream>>>(x1, wq_w, wq_b, qws, 4);
    proj_kernel<<<NK / BT, BT, 0, stream>>>(x2, wk_w, wk_b, kws, 4);
    proj_kernel<<<NK / BT, BT, 0, stream>>>(x2, wv_w, wv_b, vws, 8);

    dim3 grid(NQ / ROWS_PER_BLOCK, ksplit);
    attn_kernel<<<grid, BT, 0, stream>>>(qws, kws, vws, pws, ksplit);

    combine_kernel<<<NQ / 256, 256, 0, stream>>>(pws, out, ksplit);
}

// Round 6
// 171.159 us; speedup vs baseline: 1.1900x; 1.0092x over previous
//
#include <hip/hip_runtime.h>
#include <stdint.h>

#define NQ 8192
#define NK 8192
#define DIN 32

#define BT 256                 // threads per block (4 waves)
#define RPW 4                  // q-rows per wave (4 interleaved hash chains)
#define ROWS_PER_BLOCK 16      // 4 waves * RPW

// keep  <=>  (bits >> 9) < 6710887  <=>  bits < 6710887*512  (bit-exact, verified r2-r5)
#define KEEP_BITS 3435974144u
// fold 1/16 (score scale) and log2(e) into q so e = exp2(dot(qs, k))
#define QSCALE 0.09016844005556021f

// ---------------- threefry2x32-20, JAX partitionable path ----------------
// key = jax.random.key(42) -> (0, 42); counter (hi,lo) = (0, flat_idx)
// bits = out0 ^ out1. Same schedule as r5 (bit-exact), but each round is
// now grouped ACROSS the 4 chains (4 adds, 4 alignbits, 4 xors) so every
// dependent pair is >=4 instructions (8 cy) apart -> no VALU dep stalls.
//
// rotl(x, r) == v_alignbit_b32(x, x, 32-r):
//   rot 13,15,26,6,17,29,16,24 -> shift 19,17,6,26,15,3,16,8
// ks1 = 42, ks2 = 0x1BD11BDA ^ 42 = 0x1BD11BF0

__device__ __forceinline__ uint32_t rotl(uint32_t v, int d) {
    return __builtin_amdgcn_alignbit(v, v, 32 - d);
}

// one threefry round for 4 chains, cross-chain grouped; S = 32 - rotation
#define TF_ROUND(S) \
  "v_add_u32 %0,%0,%4\n v_add_u32 %1,%1,%5\n"                     \
  "v_add_u32 %2,%2,%6\n v_add_u32 %3,%3,%7\n"                     \
  "v_alignbit_b32 %4,%4,%4," #S "\n v_alignbit_b32 %5,%5,%5," #S "\n" \
  "v_alignbit_b32 %6,%6,%6," #S "\n v_alignbit_b32 %7,%7,%7," #S "\n" \
  "v_xor_b32 %4,%4,%0\n v_xor_b32 %5,%5,%1\n"                     \
  "v_xor_b32 %6,%6,%2\n v_xor_b32 %7,%7,%3\n"

// key injection into both halves, cross-chain grouped
#define TF_INJ(C0, C1) \
  "v_add_u32 %0," #C0 ",%0\n v_add_u32 %1," #C0 ",%1\n" \
  "v_add_u32 %2," #C0 ",%2\n v_add_u32 %3," #C0 ",%3\n" \
  "v_add_u32 %4," #C1 ",%4\n v_add_u32 %5," #C1 ",%5\n" \
  "v_add_u32 %6," #C1 ",%6\n v_add_u32 %7," #C1 ",%7\n"

// injection with c0 == 0 (skip the no-op x0 adds)
#define TF_INJ1(C1) \
  "v_add_u32 %4," #C1 ",%4\n v_add_u32 %5," #C1 ",%5\n" \
  "v_add_u32 %6," #C1 ",%6\n v_add_u32 %7," #C1 ",%7\n"

__device__ __forceinline__ void threefry4(uint32_t ctr, uint32_t bits[4]) {
    uint32_t a0, a1, a2, a3, b0, b1, b2, b3;
    // round 1 (rot 13) with x0_init = 0:  x0 = t, x1 = rotl(t,13) ^ t
    {
        const uint32_t t0 = ctr + 42u;                 // j=0: 0*NK + ks1
        const uint32_t t1 = ctr + 8234u;               // j=1: NK + 42
        const uint32_t t2 = ctr + 16426u;              // j=2
        const uint32_t t3 = ctr + 24618u;              // j=3
        a0 = t0; b0 = rotl(t0, 13) ^ t0;
        a1 = t1; b1 = rotl(t1, 13) ^ t1;
        a2 = t2; b2 = rotl(t2, 13) ^ t2;
        a3 = t3; b3 = rotl(t3, 13) ^ t3;
    }
    asm volatile(
        TF_ROUND(17) TF_ROUND(6) TF_ROUND(26)          // rounds 2-4 (rot 15,26,6)
        TF_INJ(42, 0x1BD11BF1)                         // ks1, ks2+1
        TF_ROUND(15) TF_ROUND(3) TF_ROUND(16) TF_ROUND(8)   // rounds 5-8 (17,29,16,24)
        TF_INJ(0x1BD11BF0, 2)                          // ks2, 2
        TF_ROUND(19) TF_ROUND(17) TF_ROUND(6) TF_ROUND(26)  // rounds 9-12 (13,15,26,6)
        TF_INJ1(45)                                    // 0, ks1+3
        TF_ROUND(15) TF_ROUND(3) TF_ROUND(16) TF_ROUND(8)   // rounds 13-16 (17,29,16,24)
        TF_INJ(42, 0x1BD11BF4)                         // ks1, ks2+4
        TF_ROUND(19) TF_ROUND(17) TF_ROUND(6) TF_ROUND(26)  // rounds 17-20 (13,15,26,6)
        : "+v"(a0), "+v"(a1), "+v"(a2), "+v"(a3),
          "+v"(b0), "+v"(b1), "+v"(b2), "+v"(b3));
    bits[0] = (a0 + 0x1BD11BF0u) ^ (b0 + 5u);
    bits[1] = (a1 + 0x1BD11BF0u) ^ (b1 + 5u);
    bits[2] = (a2 + 0x1BD11BF0u) ^ (b2 + 5u);
    bits[3] = (a3 + 0x1BD11BF0u) ^ (b3 + 5u);
}

__device__ __forceinline__ float fexp2(float x) {
#if __has_builtin(__builtin_amdgcn_exp2f)
    return __builtin_amdgcn_exp2f(x);
#else
    return __expf(0.6931471805599453f * x);
#endif
}

// ---------------- tiny projection: out[r][c] = x[r][:] . w[c][:] + b[c] --
__global__ void proj_kernel(const float* __restrict__ x,
                            const float* __restrict__ w,
                            const float* __restrict__ b,
                            float* __restrict__ out, int dout) {
    __shared__ __align__(16) float ws[8 * DIN];
    __shared__ float bs[8];
    const int tid = threadIdx.x;
    if (tid < dout * DIN) ws[tid] = w[tid];
    if (tid < dout) bs[tid] = b[tid];
    __syncthreads();

    const int row = blockIdx.x * BT + tid;
    const float4* xr = reinterpret_cast<const float4*>(x + (size_t)row * DIN);
    float4 xv[8];
#pragma unroll
    for (int i = 0; i < 8; ++i) xv[i] = xr[i];

    for (int c = 0; c < dout; ++c) {
        float s = bs[c];
#pragma unroll
        for (int i = 0; i < 8; ++i) {
            const float4 wv = *reinterpret_cast<const float4*>(&ws[c * DIN + i * 4]);
            s += xv[i].x * wv.x + xv[i].y * wv.y + xv[i].z * wv.z + xv[i].w * wv.w;
        }
        out[(size_t)row * dout + c] = s;
    }
}

// ---------------- fused scores+softmax+dropout+PV (k-split partials) -----
// No LDS: k/v (384 KB) are L2-resident; loads issued at loop top, consumed
// after the ~570-cycle hash block (program-order latency hiding, no copies).
__global__
__attribute__((amdgpu_flat_work_group_size(BT, BT), amdgpu_waves_per_eu(4, 4)))
void attn_kernel(
    const float* __restrict__ q,        // [NQ][4] (projection output)
    const float* __restrict__ k,        // [NK][4]
    const float* __restrict__ v,        // [NK][8]
    float* __restrict__ partial,        // [ksplit][NQ][12]: 8 nums, den
    int ksplit) {
    const int tid = threadIdx.x;
    const int lane = tid & 63;
    const int wave = tid >> 6;
    const int split = blockIdx.y;
    const int qbase = blockIdx.x * ROWS_PER_BLOCK + wave * RPW;
    const int klen = NK / ksplit;
    const int kstart = split * klen;

    float4 qs[RPW];
#pragma unroll
    for (int r = 0; r < RPW; ++r) {
        const float4 t = *reinterpret_cast<const float4*>(q + (size_t)(qbase + r) * 4);
        qs[r] = make_float4(t.x * QSCALE, t.y * QSCALE, t.z * QSCALE, t.w * QSCALE);
    }

    float4 accA[RPW], accB[RPW];
    float den[RPW];
#pragma unroll
    for (int r = 0; r < RPW; ++r) {
        accA[r] = make_float4(0.f, 0.f, 0.f, 0.f);
        accB[r] = make_float4(0.f, 0.f, 0.f, 0.f);
        den[r] = 0.f;
    }

    const float4* kp = reinterpret_cast<const float4*>(k) + (kstart + lane);
    const float4* vp = reinterpret_cast<const float4*>(v) + 2 * (size_t)(kstart + lane);
    uint32_t ctr = (uint32_t)qbase * (uint32_t)NK + (uint32_t)(kstart + lane);

    const int iters = klen / 64;
    for (int it = 0; it < iters; ++it) {
        // issue loads first; hash below provides ~570 cycles of slack
        const float4 kv = kp[(size_t)it * 64];
        const float4 va = vp[(size_t)it * 128];
        const float4 vb = vp[(size_t)it * 128 + 1];

        uint32_t bits[RPW];
        threefry4(ctr, bits);
        ctr += 64;

        float e[RPW];
#pragma unroll
        for (int r = 0; r < RPW; ++r) {
            const float s = qs[r].x * kv.x + qs[r].y * kv.y +
                            qs[r].z * kv.z + qs[r].w * kv.w;
            e[r] = fexp2(s);
        }
#pragma unroll
        for (int r = 0; r < RPW; ++r) {
            const float w = (bits[r] < KEEP_BITS) ? e[r] : 0.0f;
            den[r] += e[r];
            accA[r].x += w * va.x; accA[r].y += w * va.y;
            accA[r].z += w * va.z; accA[r].w += w * va.w;
            accB[r].x += w * vb.x; accB[r].y += w * vb.y;
            accB[r].z += w * vb.z; accB[r].w += w * vb.w;
        }
    }

    // wave-level reduction of 9 accumulators per row, write partials
#pragma unroll
    for (int r = 0; r < RPW; ++r) {
        float n0 = accA[r].x, n1 = accA[r].y, n2 = accA[r].z, n3 = accA[r].w;
        float n4 = accB[r].x, n5 = accB[r].y, n6 = accB[r].z, n7 = accB[r].w;
        float dd = den[r];
#pragma unroll
        for (int off = 32; off >= 1; off >>= 1) {
            n0 += __shfl_xor(n0, off); n1 += __shfl_xor(n1, off);
            n2 += __shfl_xor(n2, off); n3 += __shfl_xor(n3, off);
            n4 += __shfl_xor(n4, off); n5 += __shfl_xor(n5, off);
            n6 += __shfl_xor(n6, off); n7 += __shfl_xor(n7, off);
            dd += __shfl_xor(dd, off);
        }
        if (lane == 0) {
            float* p = partial + ((size_t)split * NQ + (size_t)(qbase + r)) * 12;
            p[0] = n0; p[1] = n1; p[2] = n2; p[3] = n3;
            p[4] = n4; p[5] = n5; p[6] = n6; p[7] = n7;
            p[8] = dd;
        }
    }
}

// ---------------- combine partials + final normalize ---------------------
__global__ void combine_kernel(const float* __restrict__ partial,
                               float* __restrict__ out, int ksplit) {
    const int row = blockIdx.x * 256 + threadIdx.x;
    float n[8] = {0.f, 0.f, 0.f, 0.f, 0.f, 0.f, 0.f, 0.f};
    float dd = 0.f;
    for (int s = 0; s < ksplit; ++s) {
        const float* p = partial + ((size_t)s * NQ + (size_t)row) * 12;
#pragma unroll
        for (int j = 0; j < 8; ++j) n[j] += p[j];
        dd += p[8];
    }
    const float inv = 1.0f / (0.8f * dd);
#pragma unroll
    for (int j = 0; j < 8; ++j) out[(size_t)row * 8 + j] = n[j] * inv;
}

extern "C" void kernel_launch(void* const* d_in, const int* in_sizes, int n_in,
                              void* d_out, int out_size, void* d_ws, size_t ws_size,
                              hipStream_t stream) {
    const float* x1   = (const float*)d_in[0];
    const float* x2   = (const float*)d_in[1];
    const float* wq_w = (const float*)d_in[2];
    const float* wq_b = (const float*)d_in[3];
    const float* wk_w = (const float*)d_in[4];
    const float* wk_b = (const float*)d_in[5];
    const float* wv_w = (const float*)d_in[6];
    const float* wv_b = (const float*)d_in[7];
    float* out = (float*)d_out;

    // workspace: q [8192*4] | k [8192*4] | v [8192*8] | partial [ksplit][8192][12]
    float* qws = (float*)d_ws;
    float* kws = qws + (size_t)NQ * 4;
    float* vws = kws + (size_t)NK * 4;
    float* pws = vws + (size_t)NK * 8;

    const size_t qkv_bytes = ((size_t)NQ * 4 + NK * 4 + NK * 8) * sizeof(float);
    const size_t per_split = (size_t)NQ * 12 * sizeof(float);
    int ksplit = 4;
    while (ksplit > 1 && ws_size < qkv_bytes + (size_t)ksplit * per_split) ksplit >>= 1;

    proj_kernel<<<NQ / BT, BT, 0, stream>>>(x1, wq_w, wq_b, qws, 4);
    proj_kernel<<<NK / BT, BT, 0, stream>>>(x2, wk_w, wk_b, kws, 4);
    proj_kernel<<<NK / BT, BT, 0, stream>>>(x2, wv_w, wv_b, vws, 8);

    dim3 grid(NQ / ROWS_PER_BLOCK, ksplit);
    attn_kernel<<<grid, BT, 0, stream>>>(qws, kws, vws, pws, ksplit);

    combine_kernel<<<NQ / 256, 256, 0, stream>>>(pws, out, ksplit);
}

// Round 7
// 170.383 us; speedup vs baseline: 1.1954x; 1.0046x over previous
//
#include <hip/hip_runtime.h>
#include <stdint.h>

#define NQ 8192
#define NK 8192
#define DIN 32

#define BT 256                 // threads per block (4 waves)
#define RPW 4                  // q-rows per wave (4 interleaved hash chains)
#define ROWS_PER_BLOCK 16      // 4 waves * RPW

// keep  <=>  (bits >> 9) < 6710887  <=>  bits < 6710887*512  (bit-exact, verified r2-r6)
#define KEEP_BITS 3435974144u
// fold 1/16 (score scale) and log2(e) into q so e = exp2(dot(qs, k))
#define QSCALE 0.09016844005556021f

typedef float f32x4 __attribute__((ext_vector_type(4)));

// ---------------- threefry2x32-20, JAX partitionable path ----------------
// key = jax.random.key(42) -> (0, 42); counter (hi,lo) = (0, flat_idx)
// bits = out0 ^ out1. Bit-exact schedule (verified r2-r6), cross-chain
// grouped. rotl(x,r) == v_alignbit_b32(x,x,32-r).
// ks1 = 42, ks2 = 0x1BD11BDA ^ 42 = 0x1BD11BF0

__device__ __forceinline__ uint32_t rotl(uint32_t v, int d) {
    return __builtin_amdgcn_alignbit(v, v, 32 - d);
}

#define TF_ROUND(S) \
  "v_add_u32 %0,%0,%4\n v_add_u32 %1,%1,%5\n"                     \
  "v_add_u32 %2,%2,%6\n v_add_u32 %3,%3,%7\n"                     \
  "v_alignbit_b32 %4,%4,%4," #S "\n v_alignbit_b32 %5,%5,%5," #S "\n" \
  "v_alignbit_b32 %6,%6,%6," #S "\n v_alignbit_b32 %7,%7,%7," #S "\n" \
  "v_xor_b32 %4,%4,%0\n v_xor_b32 %5,%5,%1\n"                     \
  "v_xor_b32 %6,%6,%2\n v_xor_b32 %7,%7,%3\n"

#define TF_INJ(C0, C1) \
  "v_add_u32 %0," #C0 ",%0\n v_add_u32 %1," #C0 ",%1\n" \
  "v_add_u32 %2," #C0 ",%2\n v_add_u32 %3," #C0 ",%3\n" \
  "v_add_u32 %4," #C1 ",%4\n v_add_u32 %5," #C1 ",%5\n" \
  "v_add_u32 %6," #C1 ",%6\n v_add_u32 %7," #C1 ",%7\n"

#define TF_INJ1(C1) \
  "v_add_u32 %4," #C1 ",%4\n v_add_u32 %5," #C1 ",%5\n" \
  "v_add_u32 %6," #C1 ",%6\n v_add_u32 %7," #C1 ",%7\n"

__device__ __forceinline__ void threefry4(uint32_t ctr, uint32_t bits[4]) {
    uint32_t a0, a1, a2, a3, b0, b1, b2, b3;
    // round 1 (rot 13) with x0_init = 0:  x0 = t, x1 = rotl(t,13) ^ t
    {
        const uint32_t t0 = ctr + 42u;                 // j=0: 0*NK + ks1
        const uint32_t t1 = ctr + 8234u;               // j=1: NK + 42
        const uint32_t t2 = ctr + 16426u;              // j=2
        const uint32_t t3 = ctr + 24618u;              // j=3
        a0 = t0; b0 = rotl(t0, 13) ^ t0;
        a1 = t1; b1 = rotl(t1, 13) ^ t1;
        a2 = t2; b2 = rotl(t2, 13) ^ t2;
        a3 = t3; b3 = rotl(t3, 13) ^ t3;
    }
    asm volatile(
        TF_ROUND(17) TF_ROUND(6) TF_ROUND(26)          // rounds 2-4 (rot 15,26,6)
        TF_INJ(42, 0x1BD11BF1)                         // ks1, ks2+1
        TF_ROUND(15) TF_ROUND(3) TF_ROUND(16) TF_ROUND(8)   // rounds 5-8 (17,29,16,24)
        TF_INJ(0x1BD11BF0, 2)                          // ks2, 2
        TF_ROUND(19) TF_ROUND(17) TF_ROUND(6) TF_ROUND(26)  // rounds 9-12 (13,15,26,6)
        TF_INJ1(45)                                    // 0, ks1+3
        TF_ROUND(15) TF_ROUND(3) TF_ROUND(16) TF_ROUND(8)   // rounds 13-16 (17,29,16,24)
        TF_INJ(42, 0x1BD11BF4)                         // ks1, ks2+4
        TF_ROUND(19) TF_ROUND(17) TF_ROUND(6) TF_ROUND(26)  // rounds 17-20 (13,15,26,6)
        : "+v"(a0), "+v"(a1), "+v"(a2), "+v"(a3),
          "+v"(b0), "+v"(b1), "+v"(b2), "+v"(b3));
    bits[0] = (a0 + 0x1BD11BF0u) ^ (b0 + 5u);
    bits[1] = (a1 + 0x1BD11BF0u) ^ (b1 + 5u);
    bits[2] = (a2 + 0x1BD11BF0u) ^ (b2 + 5u);
    bits[3] = (a3 + 0x1BD11BF0u) ^ (b3 + 5u);
}

__device__ __forceinline__ float fexp2(float x) {
#if __has_builtin(__builtin_amdgcn_exp2f)
    return __builtin_amdgcn_exp2f(x);
#else
    return __expf(0.6931471805599453f * x);
#endif
}

// pinned async loads: issue now, wait explicitly later (vmcnt discipline ours)
#define GLOAD(dst, voff, sbase) \
    asm volatile("global_load_dwordx4 %0, %1, %2" \
                 : "=&v"(dst) : "v"(voff), "s"(sbase))
#define GLOAD16(dst, voff, sbase) \
    asm volatile("global_load_dwordx4 %0, %1, %2 offset:16" \
                 : "=&v"(dst) : "v"(voff), "s"(sbase))

// ---------------- tiny projection: out[r][c] = x[r][:] . w[c][:] + b[c] --
__global__ void proj_kernel(const float* __restrict__ x,
                            const float* __restrict__ w,
                            const float* __restrict__ b,
                            float* __restrict__ out, int dout) {
    __shared__ __align__(16) float ws[8 * DIN];
    __shared__ float bs[8];
    const int tid = threadIdx.x;
    if (tid < dout * DIN) ws[tid] = w[tid];
    if (tid < dout) bs[tid] = b[tid];
    __syncthreads();

    const int row = blockIdx.x * BT + tid;
    const float4* xr = reinterpret_cast<const float4*>(x + (size_t)row * DIN);
    float4 xv[8];
#pragma unroll
    for (int i = 0; i < 8; ++i) xv[i] = xr[i];

    for (int c = 0; c < dout; ++c) {
        float s = bs[c];
#pragma unroll
        for (int i = 0; i < 8; ++i) {
            const float4 wv = *reinterpret_cast<const float4*>(&ws[c * DIN + i * 4]);
            s += xv[i].x * wv.x + xv[i].y * wv.y + xv[i].z * wv.z + xv[i].w * wv.w;
        }
        out[(size_t)row * dout + c] = s;
    }
}

// ---------------- fused scores+softmax+dropout+PV (k-split partials) -----
// No LDS. k/v L2-resident. Loads are inline-asm double-buffered one
// iteration ahead; volatile-asm ordering pins: load(i+1) -> hash(i) ->
// s_waitcnt vmcnt(3) -> consume(i). L2 latency hides under the hash.
__global__
__attribute__((amdgpu_flat_work_group_size(BT, BT), amdgpu_waves_per_eu(4, 4)))
void attn_kernel(
    const float* __restrict__ q,        // [NQ][4] (projection output)
    const float* __restrict__ k,        // [NK][4]
    const float* __restrict__ v,        // [NK][8]
    float* __restrict__ partial,        // [ksplit][NQ][12]: 8 nums, den
    int ksplit) {
    const int tid = threadIdx.x;
    const int lane = tid & 63;
    const int wave = tid >> 6;
    const int split = blockIdx.y;
    const int qbase = blockIdx.x * ROWS_PER_BLOCK + wave * RPW;
    const int klen = NK / ksplit;
    const int kstart = split * klen;

    float4 qs[RPW];
#pragma unroll
    for (int r = 0; r < RPW; ++r) {
        const float4 t = *reinterpret_cast<const float4*>(q + (size_t)(qbase + r) * 4);
        qs[r] = make_float4(t.x * QSCALE, t.y * QSCALE, t.z * QSCALE, t.w * QSCALE);
    }

    float4 accA[RPW], accB[RPW];
    float den[RPW];
#pragma unroll
    for (int r = 0; r < RPW; ++r) {
        accA[r] = make_float4(0.f, 0.f, 0.f, 0.f);
        accB[r] = make_float4(0.f, 0.f, 0.f, 0.f);
        den[r] = 0.f;
    }

    uint32_t ctr = (uint32_t)qbase * (uint32_t)NK + (uint32_t)(kstart + lane);
    uint32_t voff_k = (uint32_t)(kstart + lane) * 16u;   // bytes into k
    uint32_t voff_v = (uint32_t)(kstart + lane) * 32u;   // bytes into v

    const int iters = klen / 64;                          // even (>= 8)

    f32x4 kA, vaA, vbA, kB, vaB, vbB;
    // prologue: issue tile 0 into set A
    GLOAD(kA, voff_k, k);
    GLOAD(vaA, voff_v, v);
    GLOAD16(vbA, voff_v, v);
    voff_k += 1024u; voff_v += 2048u;

#define CONSUME(KV, VA, VB, BITS)                                          \
    {                                                                      \
        float e[RPW];                                                      \
        _Pragma("unroll")                                                  \
        for (int r = 0; r < RPW; ++r) {                                    \
            const float s = qs[r].x * KV[0] + qs[r].y * KV[1] +            \
                            qs[r].z * KV[2] + qs[r].w * KV[3];             \
            e[r] = fexp2(s);                                               \
        }                                                                  \
        _Pragma("unroll")                                                  \
        for (int r = 0; r < RPW; ++r) {                                    \
            const float w = (BITS[r] < KEEP_BITS) ? e[r] : 0.0f;           \
            den[r] += e[r];                                                \
            accA[r].x += w * VA[0]; accA[r].y += w * VA[1];                \
            accA[r].z += w * VA[2]; accA[r].w += w * VA[3];                \
            accB[r].x += w * VB[0]; accB[r].y += w * VB[1];                \
            accB[r].z += w * VB[2]; accB[r].w += w * VB[3];                \
        }                                                                  \
    }

    for (int it = 0; it < iters; it += 2) {
        // ---- half 1: prefetch into B, hash, wait A, consume A ----
        GLOAD(kB, voff_k, k);
        GLOAD(vaB, voff_v, v);
        GLOAD16(vbB, voff_v, v);
        voff_k += 1024u; voff_v += 2048u;

        uint32_t bits1[RPW];
        threefry4(ctr, bits1);
        ctr += 64;

        asm volatile("s_waitcnt vmcnt(3)");
        __builtin_amdgcn_sched_barrier(0);
        CONSUME(kA, vaA, vbA, bits1)

        // ---- half 2: prefetch into A, hash, wait B, consume B ----
        // (last prefetch overshoots one tile: k reads spill into the v
        //  region, v reads into the partial region of d_ws — in-bounds,
        //  values never consumed)
        GLOAD(kA, voff_k, k);
        GLOAD(vaA, voff_v, v);
        GLOAD16(vbA, voff_v, v);
        voff_k += 1024u; voff_v += 2048u;

        uint32_t bits2[RPW];
        threefry4(ctr, bits2);
        ctr += 64;

        asm volatile("s_waitcnt vmcnt(3)");
        __builtin_amdgcn_sched_barrier(0);
        CONSUME(kB, vaB, vbB, bits2)
    }
    // drain dangling prefetch before its registers can be reallocated
    asm volatile("s_waitcnt vmcnt(0)");
    __builtin_amdgcn_sched_barrier(0);
#undef CONSUME

    // wave-level reduction of 9 accumulators per row, write partials
#pragma unroll
    for (int r = 0; r < RPW; ++r) {
        float n0 = accA[r].x, n1 = accA[r].y, n2 = accA[r].z, n3 = accA[r].w;
        float n4 = accB[r].x, n5 = accB[r].y, n6 = accB[r].z, n7 = accB[r].w;
        float dd = den[r];
#pragma unroll
        for (int off = 32; off >= 1; off >>= 1) {
            n0 += __shfl_xor(n0, off); n1 += __shfl_xor(n1, off);
            n2 += __shfl_xor(n2, off); n3 += __shfl_xor(n3, off);
            n4 += __shfl_xor(n4, off); n5 += __shfl_xor(n5, off);
            n6 += __shfl_xor(n6, off); n7 += __shfl_xor(n7, off);
            dd += __shfl_xor(dd, off);
        }
        if (lane == 0) {
            float* p = partial + ((size_t)split * NQ + (size_t)(qbase + r)) * 12;
            p[0] = n0; p[1] = n1; p[2] = n2; p[3] = n3;
            p[4] = n4; p[5] = n5; p[6] = n6; p[7] = n7;
            p[8] = dd;
        }
    }
}

// ---------------- combine partials + final normalize ---------------------
__global__ void combine_kernel(const float* __restrict__ partial,
                               float* __restrict__ out, int ksplit) {
    const int row = blockIdx.x * 256 + threadIdx.x;
    float n[8] = {0.f, 0.f, 0.f, 0.f, 0.f, 0.f, 0.f, 0.f};
    float dd = 0.f;
    for (int s = 0; s < ksplit; ++s) {
        const float* p = partial + ((size_t)s * NQ + (size_t)row) * 12;
#pragma unroll
        for (int j = 0; j < 8; ++j) n[j] += p[j];
        dd += p[8];
    }
    const float inv = 1.0f / (0.8f * dd);
#pragma unroll
    for (int j = 0; j < 8; ++j) out[(size_t)row * 8 + j] = n[j] * inv;
}

extern "C" void kernel_launch(void* const* d_in, const int* in_sizes, int n_in,
                              void* d_out, int out_size, void* d_ws, size_t ws_size,
                              hipStream_t stream) {
    const float* x1   = (const float*)d_in[0];
    const float* x2   = (const float*)d_in[1];
    const float* wq_w = (const float*)d_in[2];
    const float* wq_b = (const float*)d_in[3];
    const float* wk_w = (const float*)d_in[4];
    const float* wk_b = (const float*)d_in[5];
    const float* wv_w = (const float*)d_in[6];
    const float* wv_b = (const float*)d_in[7];
    float* out = (float*)d_out;

    // workspace: q [8192*4] | k [8192*4] | v [8192*8] | partial [ksplit][8192][12]
    float* qws = (float*)d_ws;
    float* kws = qws + (size_t)NQ * 4;
    float* vws = kws + (size_t)NK * 4;
    float* pws = vws + (size_t)NK * 8;

    const size_t qkv_bytes = ((size_t)NQ * 4 + NK * 4 + NK * 8) * sizeof(float);
    const size_t per_split = (size_t)NQ * 12 * sizeof(float);
    int ksplit = 4;
    while (ksplit > 1 && ws_size < qkv_bytes + (size_t)ksplit * per_split) ksplit >>= 1;

    proj_kernel<<<NQ / BT, BT, 0, stream>>>(x1, wq_w, wq_b, qws, 4);
    proj_kernel<<<NK / BT, BT, 0, stream>>>(x2, wk_w, wk_b, kws, 4);
    proj_kernel<<<NK / BT, BT, 0, stream>>>(x2, wv_w, wv_b, vws, 8);

    dim3 grid(NQ / ROWS_PER_BLOCK, ksplit);
    attn_kernel<<<grid, BT, 0, stream>>>(qws, kws, vws, pws, ksplit);

    combine_kernel<<<NQ / 256, 256, 0, stream>>>(pws, out, ksplit);
}

// Round 9
// 169.523 us; speedup vs baseline: 1.2015x; 1.0051x over previous
//
#include <hip/hip_runtime.h>
#include <stdint.h>

#define NQ 8192
#define NK 8192
#define DIN 32

#define BT 256                 // threads per block (4 waves)
#define RPW 2                  // q-rows per wave (2 hash chains; fits 64 VGPR)
#define ROWS_PER_BLOCK 8       // 4 waves * RPW

// keep  <=>  (bits >> 9) < 6710887  <=>  bits < 6710887*512  (bit-exact, verified r2-r7)
#define KEEP_BITS 3435974144u
// fold 1/16 (score scale) and log2(e) into q so e = exp2(dot(qs, k))
#define QSCALE 0.09016844005556021f

// ---------------- threefry2x32-20, JAX partitionable path ----------------
// key = jax.random.key(42) -> (0, 42); counter (hi,lo) = (0, flat_idx)
// bits = out0 ^ out1. Bit-exact schedule (verified r2-r7), now 2 chains.
// rotl(x,r) == v_alignbit_b32(x,x,32-r).
// ks1 = 42, ks2 = 0x1BD11BDA ^ 42 = 0x1BD11BF0

__device__ __forceinline__ uint32_t rotl(uint32_t v, int d) {
    return __builtin_amdgcn_alignbit(v, v, 32 - d);
}

#define TF_ROUND2(S) \
  "v_add_u32 %0,%0,%2\n v_add_u32 %1,%1,%3\n"                          \
  "v_alignbit_b32 %2,%2,%2," #S "\n v_alignbit_b32 %3,%3,%3," #S "\n"  \
  "v_xor_b32 %2,%2,%0\n v_xor_b32 %3,%3,%1\n"

#define TF_INJ2(C0, C1) \
  "v_add_u32 %0," #C0 ",%0\n v_add_u32 %1," #C0 ",%1\n" \
  "v_add_u32 %2," #C1 ",%2\n v_add_u32 %3," #C1 ",%3\n"

#define TF_INJ12(C1) \
  "v_add_u32 %2," #C1 ",%2\n v_add_u32 %3," #C1 ",%3\n"

__device__ __forceinline__ void threefry2(uint32_t ctr, uint32_t bits[2]) {
    uint32_t a0, a1, b0, b1;
    // round 1 (rot 13) with x0_init = 0:  x0 = t, x1 = rotl(t,13) ^ t
    {
        const uint32_t t0 = ctr + 42u;                 // j=0: 0*NK + ks1
        const uint32_t t1 = ctr + 8234u;               // j=1: NK + 42
        a0 = t0; b0 = rotl(t0, 13) ^ t0;
        a1 = t1; b1 = rotl(t1, 13) ^ t1;
    }
    asm volatile(
        TF_ROUND2(17) TF_ROUND2(6) TF_ROUND2(26)          // rounds 2-4 (rot 15,26,6)
        TF_INJ2(42, 0x1BD11BF1)                           // ks1, ks2+1
        TF_ROUND2(15) TF_ROUND2(3) TF_ROUND2(16) TF_ROUND2(8)  // rounds 5-8 (17,29,16,24)
        TF_INJ2(0x1BD11BF0, 2)                            // ks2, 2
        TF_ROUND2(19) TF_ROUND2(17) TF_ROUND2(6) TF_ROUND2(26) // rounds 9-12 (13,15,26,6)
        TF_INJ12(45)                                      // 0, ks1+3
        TF_ROUND2(15) TF_ROUND2(3) TF_ROUND2(16) TF_ROUND2(8)  // rounds 13-16 (17,29,16,24)
        TF_INJ2(42, 0x1BD11BF4)                           // ks1, ks2+4
        TF_ROUND2(19) TF_ROUND2(17) TF_ROUND2(6) TF_ROUND2(26) // rounds 17-20 (13,15,26,6)
        : "+v"(a0), "+v"(a1), "+v"(b0), "+v"(b1));
    bits[0] = (a0 + 0x1BD11BF0u) ^ (b0 + 5u);
    bits[1] = (a1 + 0x1BD11BF0u) ^ (b1 + 5u);
}

__device__ __forceinline__ float fexp2(float x) {
#if __has_builtin(__builtin_amdgcn_exp2f)
    return __builtin_amdgcn_exp2f(x);
#else
    return __expf(0.6931471805599453f * x);
#endif
}

// ---------------- tiny projection: out[r][c] = x[r][:] . w[c][:] + b[c] --
__global__ void proj_kernel(const float* __restrict__ x,
                            const float* __restrict__ w,
                            const float* __restrict__ b,
                            float* __restrict__ out, int dout) {
    __shared__ __align__(16) float ws[8 * DIN];
    __shared__ float bs[8];
    const int tid = threadIdx.x;
    if (tid < dout * DIN) ws[tid] = w[tid];
    if (tid < dout) bs[tid] = b[tid];
    __syncthreads();

    const int row = blockIdx.x * BT + tid;
    const float4* xr = reinterpret_cast<const float4*>(x + (size_t)row * DIN);
    float4 xv[8];
#pragma unroll
    for (int i = 0; i < 8; ++i) xv[i] = xr[i];

    for (int c = 0; c < dout; ++c) {
        float s = bs[c];
#pragma unroll
        for (int i = 0; i < 8; ++i) {
            const float4 wv = *reinterpret_cast<const float4*>(&ws[c * DIN + i * 4]);
            s += xv[i].x * wv.x + xv[i].y * wv.y + xv[i].z * wv.z + xv[i].w * wv.w;
        }
        out[(size_t)row * dout + c] = s;
    }
}

// ---------------- fused scores+softmax+dropout+PV (k-split partials) -----
// No LDS. k/v L2-resident, plain coalesced float4 loads (compiler-managed
// waitcnt — correct under any register pressure). 8 waves/SIMD resident:
// live set ~56 VGPR fits the 64-VGPR budget of waves_per_eu(8,8) honestly.
__global__
__attribute__((amdgpu_flat_work_group_size(BT, BT), amdgpu_waves_per_eu(8, 8)))
void attn_kernel(
    const float* __restrict__ q,        // [NQ][4] (projection output)
    const float* __restrict__ k,        // [NK][4]
    const float* __restrict__ v,        // [NK][8]
    float* __restrict__ partial,        // [ksplit][NQ][12]: 8 nums, den
    int ksplit) {
    const int tid = threadIdx.x;
    const int lane = tid & 63;
    const int wave = tid >> 6;
    const int split = blockIdx.y;
    const int qbase = blockIdx.x * ROWS_PER_BLOCK + wave * RPW;
    const int klen = NK / ksplit;
    const int kstart = split * klen;

    float4 qs[RPW];
#pragma unroll
    for (int r = 0; r < RPW; ++r) {
        const float4 t = *reinterpret_cast<const float4*>(q + (size_t)(qbase + r) * 4);
        qs[r] = make_float4(t.x * QSCALE, t.y * QSCALE, t.z * QSCALE, t.w * QSCALE);
    }

    float4 accA[RPW], accB[RPW];
    float den[RPW];
#pragma unroll
    for (int r = 0; r < RPW; ++r) {
        accA[r] = make_float4(0.f, 0.f, 0.f, 0.f);
        accB[r] = make_float4(0.f, 0.f, 0.f, 0.f);
        den[r] = 0.f;
    }

    const float4* kp = reinterpret_cast<const float4*>(k) + (kstart + lane);
    const float4* vp = reinterpret_cast<const float4*>(v) + 2 * (size_t)(kstart + lane);
    uint32_t ctr = (uint32_t)qbase * (uint32_t)NK + (uint32_t)(kstart + lane);

    const int iters = klen / 64;
    for (int it = 0; it < iters; ++it) {
        const float4 kv = kp[(size_t)it * 64];
        const float4 va = vp[(size_t)it * 128];
        const float4 vb = vp[(size_t)it * 128 + 1];

        uint32_t bits[RPW];
        threefry2(ctr, bits);
        ctr += 64;

        float e[RPW];
#pragma unroll
        for (int r = 0; r < RPW; ++r) {
            const float s = qs[r].x * kv.x + qs[r].y * kv.y +
                            qs[r].z * kv.z + qs[r].w * kv.w;
            e[r] = fexp2(s);
        }
#pragma unroll
        for (int r = 0; r < RPW; ++r) {
            const float w = (bits[r] < KEEP_BITS) ? e[r] : 0.0f;
            den[r] += e[r];
            accA[r].x += w * va.x; accA[r].y += w * va.y;
            accA[r].z += w * va.z; accA[r].w += w * va.w;
            accB[r].x += w * vb.x; accB[r].y += w * vb.y;
            accB[r].z += w * vb.z; accB[r].w += w * vb.w;
        }
    }

    // wave-level reduction of 9 accumulators per row, write partials
#pragma unroll
    for (int r = 0; r < RPW; ++r) {
        float n0 = accA[r].x, n1 = accA[r].y, n2 = accA[r].z, n3 = accA[r].w;
        float n4 = accB[r].x, n5 = accB[r].y, n6 = accB[r].z, n7 = accB[r].w;
        float dd = den[r];
#pragma unroll
        for (int off = 32; off >= 1; off >>= 1) {
            n0 += __shfl_xor(n0, off); n1 += __shfl_xor(n1, off);
            n2 += __shfl_xor(n2, off); n3 += __shfl_xor(n3, off);
            n4 += __shfl_xor(n4, off); n5 += __shfl_xor(n5, off);
            n6 += __shfl_xor(n6, off); n7 += __shfl_xor(n7, off);
            dd += __shfl_xor(dd, off);
        }
        if (lane == 0) {
            float* p = partial + ((size_t)split * NQ + (size_t)(qbase + r)) * 12;
            p[0] = n0; p[1] = n1; p[2] = n2; p[3] = n3;
            p[4] = n4; p[5] = n5; p[6] = n6; p[7] = n7;
            p[8] = dd;
        }
    }
}

// ---------------- combine partials + final normalize ---------------------
__global__ void combine_kernel(const float* __restrict__ partial,
                               float* __restrict__ out, int ksplit) {
    const int row = blockIdx.x * 256 + threadIdx.x;
    float n[8] = {0.f, 0.f, 0.f, 0.f, 0.f, 0.f, 0.f, 0.f};
    float dd = 0.f;
    for (int s = 0; s < ksplit; ++s) {
        const float* p = partial + ((size_t)s * NQ + (size_t)row) * 12;
#pragma unroll
        for (int j = 0; j < 8; ++j) n[j] += p[j];
        dd += p[8];
    }
    const float inv = 1.0f / (0.8f * dd);
#pragma unroll
    for (int j = 0; j < 8; ++j) out[(size_t)row * 8 + j] = n[j] * inv;
}

extern "C" void kernel_launch(void* const* d_in, const int* in_sizes, int n_in,
                              void* d_out, int out_size, void* d_ws, size_t ws_size,
                              hipStream_t stream) {
    const float* x1   = (const float*)d_in[0];
    const float* x2   = (const float*)d_in[1];
    const float* wq_w = (const float*)d_in[2];
    const float* wq_b = (const float*)d_in[3];
    const float* wk_w = (const float*)d_in[4];
    const float* wk_b = (const float*)d_in[5];
    const float* wv_w = (const float*)d_in[6];
    const float* wv_b = (const float*)d_in[7];
    float* out = (float*)d_out;

    // workspace: q [8192*4] | k [8192*4] | v [8192*8] | partial [ksplit][8192][12]
    float* qws = (float*)d_ws;
    float* kws = qws + (size_t)NQ * 4;
    float* vws = kws + (size_t)NK * 4;
    float* pws = vws + (size_t)NK * 8;

    const size_t qkv_bytes = ((size_t)NQ * 4 + NK * 4 + NK * 8) * sizeof(float);
    const size_t per_split = (size_t)NQ * 12 * sizeof(float);
    int ksplit = 4;
    while (ksplit > 1 && ws_size < qkv_bytes + (size_t)ksplit * per_split) ksplit >>= 1;

    proj_kernel<<<NQ / BT, BT, 0, stream>>>(x1, wq_w, wq_b, qws, 4);
    proj_kernel<<<NK / BT, BT, 0, stream>>>(x2, wk_w, wk_b, kws, 4);
    proj_kernel<<<NK / BT, BT, 0, stream>>>(x2, wv_w, wv_b, vws, 8);

    dim3 grid(NQ / ROWS_PER_BLOCK, ksplit);
    attn_kernel<<<grid, BT, 0, stream>>>(qws, kws, vws, pws, ksplit);

    combine_kernel<<<NQ / 256, 256, 0, stream>>>(pws, out, ksplit);
}

// Round 10
// 162.956 us; speedup vs baseline: 1.2499x; 1.0403x over previous
//
#include <hip/hip_runtime.h>
#include <stdint.h>

#define NQ 8192
#define NK 8192
#define DIN 32

#define BT 256                 // threads per block (4 waves)
#define RPW 2                  // q-rows per wave (2 hash chains; fits 64 VGPR)
#define ROWS_PER_BLOCK 8       // 4 waves * RPW

// keep  <=>  (bits >> 9) < 6710887  <=>  bits < 6710887*512  (bit-exact, verified r2-r9)
#define KEEP_BITS 3435974144u
// fold 1/16 (score scale) and log2(e) into q so e = exp2(dot(qs, k))
#define QSCALE 0.09016844005556021f

typedef float f32x2 __attribute__((ext_vector_type(2)));

// ---------------- threefry2x32-20, JAX partitionable path ----------------
// key = jax.random.key(42) -> (0, 42); counter (hi,lo) = (0, flat_idx)
// bits = out0 ^ out1. Bit-exact schedule (verified r2-r9), 2 chains,
// key-injections FOLDED into the next round's x0-add via v_add3_u32
// (pure mod-2^32 reassociation - same bits).
// rotl(x,r) == v_alignbit_b32(x,x,32-r):
//   rot 13,15,26,6,17,29,16,24 -> S 19,17,6,26,15,3,16,8
// ks1 = 42, ks2 = 0x1BD11BDA ^ 42 = 0x1BD11BF0 (SGPR %4 below)

__device__ __forceinline__ uint32_t rotl(uint32_t v, int d) {
    return __builtin_amdgcn_alignbit(v, v, 32 - d);
}

#define TF_ROUND2(S) \
  "v_add_u32 %0,%0,%2\n v_add_u32 %1,%1,%3\n"                          \
  "v_alignbit_b32 %2,%2,%2," #S "\n v_alignbit_b32 %3,%3,%3," #S "\n"  \
  "v_xor_b32 %2,%2,%0\n v_xor_b32 %3,%3,%1\n"

// inject (c0 inline-const, c1) folded into round with shift S
#define TF_RINJ2(C0, C1, S) \
  "v_add_u32 %2," #C1 ",%2\n v_add_u32 %3," #C1 ",%3\n"                \
  "v_add3_u32 %0,%0," #C0 ",%2\n v_add3_u32 %1,%1," #C0 ",%3\n"        \
  "v_alignbit_b32 %2,%2,%2," #S "\n v_alignbit_b32 %3,%3,%3," #S "\n"  \
  "v_xor_b32 %2,%2,%0\n v_xor_b32 %3,%3,%1\n"

// inject (c0 = ks2 from SGPR %4, c1) folded into round with shift S
#define TF_RINJS2(C1, S) \
  "v_add_u32 %2," #C1 ",%2\n v_add_u32 %3," #C1 ",%3\n"                \
  "v_add3_u32 %0,%0,%4,%2\n v_add3_u32 %1,%1,%4,%3\n"                  \
  "v_alignbit_b32 %2,%2,%2," #S "\n v_alignbit_b32 %3,%3,%3," #S "\n"  \
  "v_xor_b32 %2,%2,%0\n v_xor_b32 %3,%3,%1\n"

// inject (c0 = 0, c1) folded into round with shift S
#define TF_RINJ02(C1, S) \
  "v_add_u32 %2," #C1 ",%2\n v_add_u32 %3," #C1 ",%3\n"                \
  "v_add_u32 %0,%0,%2\n v_add_u32 %1,%1,%3\n"                          \
  "v_alignbit_b32 %2,%2,%2," #S "\n v_alignbit_b32 %3,%3,%3," #S "\n"  \
  "v_xor_b32 %2,%2,%0\n v_xor_b32 %3,%3,%1\n"

// t0 = ctr + 42, t1 = ctr + NK + 42 (maintained incrementally by caller)
__device__ __forceinline__ void threefry2(uint32_t t0, uint32_t t1,
                                          uint32_t bits[2]) {
    uint32_t a0, a1, b0, b1;
    // round 1 (rot 13) with x0_init = 0:  x0 = t, x1 = rotl(t,13) ^ t
    a0 = t0; b0 = rotl(t0, 13) ^ t0;
    a1 = t1; b1 = rotl(t1, 13) ^ t1;
    asm(
        TF_ROUND2(17) TF_ROUND2(6) TF_ROUND2(26)        // r2-r4  (rot 15,26,6)
        TF_RINJ2(42, 0x1BD11BF1, 15)                    // inj(ks1,ks2+1) + r5 (rot17)
        TF_ROUND2(3) TF_ROUND2(16) TF_ROUND2(8)         // r6-r8  (rot 29,16,24)
        TF_RINJS2(2, 19)                                // inj(ks2,2)    + r9 (rot13)
        TF_ROUND2(17) TF_ROUND2(6) TF_ROUND2(26)        // r10-r12 (rot 15,26,6)
        TF_RINJ02(45, 15)                               // inj(0,ks1+3)  + r13 (rot17)
        TF_ROUND2(3) TF_ROUND2(16) TF_ROUND2(8)         // r14-r16 (rot 29,16,24)
        TF_RINJ2(42, 0x1BD11BF4, 19)                    // inj(ks1,ks2+4)+ r17 (rot13)
        TF_ROUND2(17) TF_ROUND2(6) TF_ROUND2(26)        // r18-r20 (rot 15,26,6)
        : "+v"(a0), "+v"(a1), "+v"(b0), "+v"(b1)
        : "s"(0x1BD11BF0u));
    bits[0] = (a0 + 0x1BD11BF0u) ^ (b0 + 5u);
    bits[1] = (a1 + 0x1BD11BF0u) ^ (b1 + 5u);
}

__device__ __forceinline__ float fexp2(float x) {
#if __has_builtin(__builtin_amdgcn_exp2f)
    return __builtin_amdgcn_exp2f(x);
#else
    return __expf(0.6931471805599453f * x);
#endif
}

// packed f32 helpers (v_pk_* are full-rate on CDNA, IEEE-identical per half)
#define PK_MUL(D, A, B) \
    asm("v_pk_mul_f32 %0,%1,%2" : "=v"(D) : "v"(A), "v"(B))
#define PK_FMA(ACC, A, B) \
    asm("v_pk_fma_f32 %0,%1,%2,%0" : "+v"(ACC) : "v"(A), "v"(B))

// ---------------- tiny projection: out[r][c] = x[r][:] . w[c][:] + b[c] --
__global__ void proj_kernel(const float* __restrict__ x,
                            const float* __restrict__ w,
                            const float* __restrict__ b,
                            float* __restrict__ out, int dout) {
    __shared__ __align__(16) float ws[8 * DIN];
    __shared__ float bs[8];
    const int tid = threadIdx.x;
    if (tid < dout * DIN) ws[tid] = w[tid];
    if (tid < dout) bs[tid] = b[tid];
    __syncthreads();

    const int row = blockIdx.x * BT + tid;
    const float4* xr = reinterpret_cast<const float4*>(x + (size_t)row * DIN);
    float4 xv[8];
#pragma unroll
    for (int i = 0; i < 8; ++i) xv[i] = xr[i];

    for (int c = 0; c < dout; ++c) {
        float s = bs[c];
#pragma unroll
        for (int i = 0; i < 8; ++i) {
            const float4 wv = *reinterpret_cast<const float4*>(&ws[c * DIN + i * 4]);
            s += xv[i].x * wv.x + xv[i].y * wv.y + xv[i].z * wv.z + xv[i].w * wv.w;
        }
        out[(size_t)row * dout + c] = s;
    }
}

// ---------------- fused scores+softmax+dropout+PV (k-split partials) -----
// No LDS. k/v L2-resident, plain coalesced f32x2 loads (compiler-managed).
// 8 waves/SIMD resident; VALU-issue-bound -> minimize instructions/element:
// hash 67 (asm, folded injections) + ~12 packed-f32 rest.
__global__
__attribute__((amdgpu_flat_work_group_size(BT, BT), amdgpu_waves_per_eu(8, 8)))
void attn_kernel(
    const float* __restrict__ q,        // [NQ][4] (projection output)
    const float* __restrict__ k,        // [NK][4]
    const float* __restrict__ v,        // [NK][8]
    float* __restrict__ partial,        // [ksplit][NQ][12]: 8 nums, den
    int ksplit) {
    const int tid = threadIdx.x;
    const int lane = tid & 63;
    const int wave = tid >> 6;
    const int split = blockIdx.y;
    const int qbase = blockIdx.x * ROWS_PER_BLOCK + wave * RPW;
    const int klen = NK / ksplit;
    const int kstart = split * klen;

    f32x2 q01[RPW], q23[RPW];
#pragma unroll
    for (int r = 0; r < RPW; ++r) {
        const float4 t = *reinterpret_cast<const float4*>(q + (size_t)(qbase + r) * 4);
        q01[r][0] = t.x * QSCALE; q01[r][1] = t.y * QSCALE;
        q23[r][0] = t.z * QSCALE; q23[r][1] = t.w * QSCALE;
    }

    // acc pairs: [r] x {va01, va23, vb01, vb23}
    f32x2 acc0[RPW], acc1[RPW], acc2[RPW], acc3[RPW];
    f32x2 denp = {0.f, 0.f};
#pragma unroll
    for (int r = 0; r < RPW; ++r) {
        acc0[r] = (f32x2){0.f, 0.f}; acc1[r] = (f32x2){0.f, 0.f};
        acc2[r] = (f32x2){0.f, 0.f}; acc3[r] = (f32x2){0.f, 0.f};
    }

    const f32x2* kp2 = reinterpret_cast<const f32x2*>(k) + 2 * (size_t)(kstart + lane);
    const f32x2* vp2 = reinterpret_cast<const f32x2*>(v) + 4 * (size_t)(kstart + lane);
    const uint32_t ctr0 = (uint32_t)qbase * (uint32_t)NK + (uint32_t)(kstart + lane);
    uint32_t t0 = ctr0 + 42u;            // chain j=0: ctr + ks1
    uint32_t t1 = ctr0 + 8234u;          // chain j=1: ctr + NK + ks1

    const int iters = klen / 64;
    for (int it = 0; it < iters; ++it) {
        const f32x2 k01  = kp2[(size_t)it * 128];
        const f32x2 k23  = kp2[(size_t)it * 128 + 1];
        const f32x2 va01 = vp2[(size_t)it * 256];
        const f32x2 va23 = vp2[(size_t)it * 256 + 1];
        const f32x2 vb01 = vp2[(size_t)it * 256 + 2];
        const f32x2 vb23 = vp2[(size_t)it * 256 + 3];

        uint32_t bits[RPW];
        threefry2(t0, t1, bits);
        t0 += 64u; t1 += 64u;

        f32x2 ep;
#pragma unroll
        for (int r = 0; r < RPW; ++r) {
            f32x2 s01;
            PK_MUL(s01, q01[r], k01);
            PK_FMA(s01, q23[r], k23);
            ep[r] = fexp2(s01[0] + s01[1]);
        }
        denp += ep;                       // packed add (per-component order kept)
#pragma unroll
        for (int r = 0; r < RPW; ++r) {
            const float w = (bits[r] < KEEP_BITS) ? ep[r] : 0.0f;
            const f32x2 wp = {w, w};
            PK_FMA(acc0[r], va01, wp);
            PK_FMA(acc1[r], va23, wp);
            PK_FMA(acc2[r], vb01, wp);
            PK_FMA(acc3[r], vb23, wp);
        }
    }

    // wave-level reduction of 9 accumulators per row, write partials
#pragma unroll
    for (int r = 0; r < RPW; ++r) {
        float n0 = acc0[r][0], n1 = acc0[r][1], n2 = acc1[r][0], n3 = acc1[r][1];
        float n4 = acc2[r][0], n5 = acc2[r][1], n6 = acc3[r][0], n7 = acc3[r][1];
        float dd = denp[r];
#pragma unroll
        for (int off = 32; off >= 1; off >>= 1) {
            n0 += __shfl_xor(n0, off); n1 += __shfl_xor(n1, off);
            n2 += __shfl_xor(n2, off); n3 += __shfl_xor(n3, off);
            n4 += __shfl_xor(n4, off); n5 += __shfl_xor(n5, off);
            n6 += __shfl_xor(n6, off); n7 += __shfl_xor(n7, off);
            dd += __shfl_xor(dd, off);
        }
        if (lane == 0) {
            float* p = partial + ((size_t)split * NQ + (size_t)(qbase + r)) * 12;
            p[0] = n0; p[1] = n1; p[2] = n2; p[3] = n3;
            p[4] = n4; p[5] = n5; p[6] = n6; p[7] = n7;
            p[8] = dd;
        }
    }
}

// ---------------- combine partials + final normalize ---------------------
__global__ void combine_kernel(const float* __restrict__ partial,
                               float* __restrict__ out, int ksplit) {
    const int row = blockIdx.x * 256 + threadIdx.x;
    float n[8] = {0.f, 0.f, 0.f, 0.f, 0.f, 0.f, 0.f, 0.f};
    float dd = 0.f;
    for (int s = 0; s < ksplit; ++s) {
        const float* p = partial + ((size_t)s * NQ + (size_t)row) * 12;
#pragma unroll
        for (int j = 0; j < 8; ++j) n[j] += p[j];
        dd += p[8];
    }
    const float inv = 1.0f / (0.8f * dd);
#pragma unroll
    for (int j = 0; j < 8; ++j) out[(size_t)row * 8 + j] = n[j] * inv;
}

extern "C" void kernel_launch(void* const* d_in, const int* in_sizes, int n_in,
                              void* d_out, int out_size, void* d_ws, size_t ws_size,
                              hipStream_t stream) {
    const float* x1   = (const float*)d_in[0];
    const float* x2   = (const float*)d_in[1];
    const float* wq_w = (const float*)d_in[2];
    const float* wq_b = (const float*)d_in[3];
    const float* wk_w = (const float*)d_in[4];
    const float* wk_b = (const float*)d_in[5];
    const float* wv_w = (const float*)d_in[6];
    const float* wv_b = (const float*)d_in[7];
    float* out = (float*)d_out;

    // workspace: q [8192*4] | k [8192*4] | v [8192*8] | partial [ksplit][8192][12]
    float* qws = (float*)d_ws;
    float* kws = qws + (size_t)NQ * 4;
    float* vws = kws + (size_t)NK * 4;
    float* pws = vws + (size_t)NK * 8;

    const size_t qkv_bytes = ((size_t)NQ * 4 + NK * 4 + NK * 8) * sizeof(float);
    const size_t per_split = (size_t)NQ * 12 * sizeof(float);
    int ksplit = 4;
    while (ksplit > 1 && ws_size < qkv_bytes + (size_t)ksplit * per_split) ksplit >>= 1;

    proj_kernel<<<NQ / BT, BT, 0, stream>>>(x1, wq_w, wq_b, qws, 4);
    proj_kernel<<<NK / BT, BT, 0, stream>>>(x2, wk_w, wk_b, kws, 4);
    proj_kernel<<<NK / BT, BT, 0, stream>>>(x2, wv_w, wv_b, vws, 8);

    dim3 grid(NQ / ROWS_PER_BLOCK, ksplit);
    attn_kernel<<<grid, BT, 0, stream>>>(qws, kws, vws, pws, ksplit);

    combine_kernel<<<NQ / 256, 256, 0, stream>>>(pws, out, ksplit);
}